// Round 1
// baseline (864.110 us; speedup 1.0000x reference)
//
#include <hip/hip_runtime.h>
#include <math.h>

// Problem constants
constexpr int B = 256;
constexpr int C = 512;
constexpr int N = 512;
constexpr int K = 256;   // = B

// ws layout (floats)
constexpr size_t OFF_CLIPN = 0;                        // B*C
constexpr size_t OFF_INV   = OFF_CLIPN + (size_t)B*C;  // B*N
constexpr size_t OFF_GRAW  = OFF_INV   + (size_t)B*N;  // B*C
constexpr size_t OFF_GNORM = OFF_GRAW  + (size_t)B*C;  // B*C
constexpr size_t OFF_SGLOB = OFF_GNORM + (size_t)B*C;  // B*K
constexpr size_t OFF_SSOFT = OFF_SGLOB + (size_t)B*K;  // B*K
constexpr size_t OFF_SHARD = OFF_SSOFT + (size_t)B*K;  // B*K
constexpr size_t OFF_MISC  = OFF_SHARD + (size_t)B*K;  // 7: [0]=scale, [1..6]=focal sums
// total = 720903 floats = 2.88 MB

__device__ __forceinline__ float wave_reduce_sum(float v) {
  #pragma unroll
  for (int off = 32; off > 0; off >>= 1) v += __shfl_xor(v, off, 64);
  return v;
}
__device__ __forceinline__ float wave_reduce_max(float v) {
  #pragma unroll
  for (int off = 32; off > 0; off >>= 1) v = fmaxf(v, __shfl_xor(v, off, 64));
  return v;
}

// ---------------- K0: scale + zero focal accumulators ----------------
__global__ void k_misc(const float* __restrict__ ls, float* __restrict__ misc) {
  int t = threadIdx.x;
  if (t == 0) misc[0] = fminf(fmaxf(expf(ls[0]), 0.01f), 100.0f);
  if (t >= 1 && t < 7) misc[t] = 0.0f;
}

// ---------------- K1: l2-normalize 256 rows of 512 ----------------
__global__ __launch_bounds__(256) void k_rownorm(const float* __restrict__ src,
                                                 float* __restrict__ dst) {
  int b = blockIdx.x, t = threadIdx.x;
  float x0 = src[(size_t)b * C + t];
  float x1 = src[(size_t)b * C + t + 256];
  __shared__ float red[4];
  float w = wave_reduce_sum(x0 * x0 + x1 * x1);
  if ((t & 63) == 0) red[t >> 6] = w;
  __syncthreads();
  float tot = red[0] + red[1] + red[2] + red[3];
  float r = 1.0f / fmaxf(sqrtf(tot), 1e-12f);
  dst[(size_t)b * C + t] = x0 * r;
  dst[(size_t)b * C + t + 256] = x1 * r;
}

// ---------------- K2: yolo column inverse norms: inv[b][n] ----------------
__global__ __launch_bounds__(512) void k_colnorm(const float* __restrict__ yolo,
                                                 float* __restrict__ inv) {
  int b = blockIdx.x, t = threadIdx.x;
  int cq = t >> 7;        // 0..3 (c quarter)
  int nq = t & 127;       // 0..127 (n quad)
  const float* p = yolo + (size_t)b * C * N + (size_t)cq * 128 * N + nq * 4;
  float4 ss = {0.f, 0.f, 0.f, 0.f};
  #pragma unroll 8
  for (int c = 0; c < 128; c++) {
    float4 v = *(const float4*)(p + (size_t)c * N);
    ss.x += v.x * v.x; ss.y += v.y * v.y; ss.z += v.z * v.z; ss.w += v.w * v.w;
  }
  __shared__ float4 sm[4][128];
  sm[cq][nq] = ss;
  __syncthreads();
  if (t < 128) {
    float4 a = sm[0][t], b4 = sm[1][t], c4 = sm[2][t], d4 = sm[3][t];
    float4 r;
    r.x = 1.0f / fmaxf(sqrtf(a.x + b4.x + c4.x + d4.x), 1e-12f);
    r.y = 1.0f / fmaxf(sqrtf(a.y + b4.y + c4.y + d4.y), 1e-12f);
    r.z = 1.0f / fmaxf(sqrtf(a.z + b4.z + c4.z + d4.z), 1e-12f);
    r.w = 1.0f / fmaxf(sqrtf(a.w + b4.w + c4.w + d4.w), 1e-12f);
    *(float4*)(inv + (size_t)b * N + t * 4) = r;
  }
}

// ---------------- K3: graw[b][c] = (1/N) * sum_n yolo[b][c][n]*inv[b][n] ----------------
__global__ __launch_bounds__(512) void k_global_acc(const float* __restrict__ yolo,
                                                    const float* __restrict__ inv,
                                                    float* __restrict__ graw) {
  int b = blockIdx.y;
  int c0 = blockIdx.x * 32;
  int t = threadIdx.x;
  int ci = t >> 7;    // 0..3
  int nq = t & 127;   // 0..127
  float4 i4 = *(const float4*)(inv + (size_t)b * N + nq * 4);
  __shared__ float sm[8];
  const float* base = yolo + (size_t)b * C * N;
  for (int r = 0; r < 8; r++) {
    int c = c0 + r * 4 + ci;
    float4 v = *(const float4*)(base + (size_t)c * N + nq * 4);
    float p = v.x * i4.x + v.y * i4.y + v.z * i4.z + v.w * i4.w;
    float w = wave_reduce_sum(p);
    if ((t & 63) == 0) sm[t >> 6] = w;
    __syncthreads();
    if (t < 4) graw[(size_t)b * C + c0 + r * 4 + t] =
        (sm[2 * t] + sm[2 * t + 1]) * (1.0f / (float)N);
    __syncthreads();
  }
}

// ---------------- K4: Sglob[i][k] = scale * dot(gnorm[i], clipn[k]) ----------------
__global__ __launch_bounds__(256) void k_simglobal(const float* __restrict__ gnorm,
                                                   const float* __restrict__ clipn,
                                                   const float* __restrict__ misc,
                                                   float* __restrict__ Sglob) {
  int i = blockIdx.x, k = threadIdx.x;
  __shared__ float g[C];
  g[k] = gnorm[(size_t)i * C + k];
  g[k + 256] = gnorm[(size_t)i * C + k + 256];
  __syncthreads();
  float scale = misc[0];
  const float* cr = clipn + (size_t)k * C;
  float acc = 0.f;
  #pragma unroll 4
  for (int c = 0; c < C; c += 4) {
    float4 cv = *(const float4*)(cr + c);
    acc += cv.x * g[c] + cv.y * g[c + 1] + cv.z * g[c + 2] + cv.w * g[c + 3];
  }
  Sglob[(size_t)i * K + k] = acc * scale;
}

// ---------------- K5: main GEMM + online logsumexp/max over n ----------------
constexpr int TN = 128;       // n tile
constexpr int CC = 32;        // c chunk
constexpr int XS = TN + 4;    // xt row stride

__global__ __launch_bounds__(512, 2) void k_main(const float* __restrict__ yolo,
                                                 const float* __restrict__ clipn,
                                                 const float* __restrict__ inv,
                                                 const float* __restrict__ misc,
                                                 float* __restrict__ Ssoft,
                                                 float* __restrict__ Shard) {
  int b = blockIdx.x;
  int t = threadIdx.x;
  int kg = t >> 3;   // 0..63  -> k = kg*4 + kk
  int ng = t & 7;    // 0..7   -> n = ng*4 + q*32 + j (q<4, j<4)
  __shared__ float xt[CC][XS];     // 16.9 KB
  __shared__ float ct[CC][K];      // 32 KB  [c][k], reused as merge buffers at end
  __shared__ float invt[TN];
  const float scale = misc[0];
  float m[4], s[4], h[4];
  #pragma unroll
  for (int kk = 0; kk < 4; kk++) { m[kk] = -1e30f; s[kk] = 0.f; h[kk] = -1e30f; }
  const float* ybase = yolo + (size_t)b * C * N;

  for (int n0 = 0; n0 < N; n0 += TN) {
    __syncthreads();   // previous tile's epilogue readers done before invt overwrite
    if (t < TN) invt[t] = inv[(size_t)b * N + n0 + t] * scale;
    float acc[4][16];
    #pragma unroll
    for (int kk = 0; kk < 4; kk++)
      #pragma unroll
      for (int j = 0; j < 16; j++) acc[kk][j] = 0.f;

    for (int c0 = 0; c0 < C; c0 += CC) {
      __syncthreads();   // previous chunk compute done before restage
      {  // stage x tile: 32 c x 128 n
        int i = t >> 4, seg = t & 15;
        const float* p = ybase + (size_t)(c0 + i) * N + n0 + seg * 8;
        float4 a = *(const float4*)p;
        float4 b4 = *(const float4*)(p + 4);
        *(float4*)&xt[i][seg * 8] = a;
        *(float4*)&xt[i][seg * 8 + 4] = b4;
      }
      {  // stage clip tile transposed: ct[c][k]
        int k = t >> 1, ch = (t & 1) << 4;
        const float* p = clipn + (size_t)k * C + c0 + ch;
        #pragma unroll
        for (int q = 0; q < 4; q++) {
          float4 v = *(const float4*)(p + q * 4);
          ct[ch + q * 4 + 0][k] = v.x;
          ct[ch + q * 4 + 1][k] = v.y;
          ct[ch + q * 4 + 2][k] = v.z;
          ct[ch + q * 4 + 3][k] = v.w;
        }
      }
      __syncthreads();
      #pragma unroll 2
      for (int i = 0; i < CC; i++) {
        float4 cv = *(const float4*)&ct[i][kg << 2];
        float xv[16];
        #pragma unroll
        for (int q = 0; q < 4; q++)
          *(float4*)&xv[q * 4] = *(const float4*)&xt[i][(ng << 2) + (q << 5)];
        #pragma unroll
        for (int j = 0; j < 16; j++) {
          acc[0][j] = fmaf(cv.x, xv[j], acc[0][j]);
          acc[1][j] = fmaf(cv.y, xv[j], acc[1][j]);
          acc[2][j] = fmaf(cv.z, xv[j], acc[2][j]);
          acc[3][j] = fmaf(cv.w, xv[j], acc[3][j]);
        }
      }
    }
    // tile epilogue: fold colnorm+scale, online logsumexp/max over this tile's n's
    #pragma unroll
    for (int kk = 0; kk < 4; kk++) {
      #pragma unroll
      for (int q = 0; q < 4; q++) {
        #pragma unroll
        for (int j = 0; j < 4; j++) {
          float v = acc[kk][q * 4 + j] * invt[(ng << 2) + (q << 5) + j];
          h[kk] = fmaxf(h[kk], v);
          float mn = fmaxf(m[kk], v);
          s[kk] = s[kk] * __expf(m[kk] - mn) + __expf(v - mn);
          m[kk] = mn;
        }
      }
    }
  }
  // merge the 8 n-groups per k (reuse ct LDS as merge buffers)
  __syncthreads();
  float* mbuf = &ct[0][0];        // [k*8+g], 2048 floats
  float* sbuf = mbuf + 2048;
  float* hbuf = mbuf + 4096;
  #pragma unroll
  for (int kk = 0; kk < 4; kk++) {
    int k = kg * 4 + kk;
    mbuf[k * 8 + ng] = m[kk];
    sbuf[k * 8 + ng] = s[kk];
    hbuf[k * 8 + ng] = h[kk];
  }
  __syncthreads();
  if (t < K) {
    float M2 = -1e30f, H = -1e30f, S = 0.f;
    #pragma unroll
    for (int g = 0; g < 8; g++) M2 = fmaxf(M2, mbuf[t * 8 + g]);
    #pragma unroll
    for (int g = 0; g < 8; g++) {
      S += sbuf[t * 8 + g] * __expf(mbuf[t * 8 + g] - M2);
      H = fmaxf(H, hbuf[t * 8 + g]);
    }
    Ssoft[(size_t)b * K + t] = M2 + __logf(S);
    Shard[(size_t)b * K + t] = H;
  }
}

// ---------------- K6: focal CE per row/col of each 256x256 matrix ----------------
__global__ __launch_bounds__(256) void k_focal(const float* __restrict__ Sglob,
                                               const float* __restrict__ Ssoft,
                                               const float* __restrict__ Shard,
                                               float* __restrict__ misc) {
  int job = blockIdx.y;   // 0..5: {glob,globT,soft,softT,hard,hardT}
  int i = blockIdx.x;
  int t = threadIdx.x;
  const float* M = job < 2 ? Sglob : (job < 4 ? Ssoft : Shard);
  float v = (job & 1) ? M[(size_t)t * K + i] : M[(size_t)i * K + t];
  __shared__ float red[4];
  float mx = wave_reduce_max(v);
  if ((t & 63) == 0) red[t >> 6] = mx;
  __syncthreads();
  mx = fmaxf(fmaxf(red[0], red[1]), fmaxf(red[2], red[3]));
  __syncthreads();
  float sv = wave_reduce_sum(v);
  if ((t & 63) == 0) red[t >> 6] = sv;
  __syncthreads();
  float sumv = red[0] + red[1] + red[2] + red[3];
  __syncthreads();
  float se = wave_reduce_sum(expf(v - mx));
  if ((t & 63) == 0) red[t >> 6] = se;
  __syncthreads();
  if (t == 0) {
    float sumexp = red[0] + red[1] + red[2] + red[3];
    float logZ = mx + logf(sumexp);
    float diag = M[(size_t)i * K + i];
    float nll = logZ - diag;                      // -log_p[label]
    float smooth = logZ - sumv * (1.0f / 256.0f); // -mean(log_p)
    float ce = 0.75f * nll + 0.25f * smooth;
    float pt = expf(-ce);
    float fo = (1.0f - pt) * (1.0f - pt) * ce;
    atomicAdd(&misc[1 + job], fo);
  }
}

// ---------------- K7: combine ----------------
__global__ void k_finish(const float* __restrict__ misc, float* __restrict__ out) {
  float lg = misc[1] + misc[2];
  float ls = misc[3] + misc[4];
  float lh = misc[5] + misc[6];
  out[0] = (0.2f * lg + 0.3f * ls + 0.5f * lh) * 0.5f * (1.0f / 256.0f);
}

extern "C" void kernel_launch(void* const* d_in, const int* in_sizes, int n_in,
                              void* d_out, int out_size, void* d_ws, size_t ws_size,
                              hipStream_t stream) {
  const float* yolo = (const float*)d_in[0];   // (B, C, N)
  const float* clip = (const float*)d_in[1];   // (B, C)
  const float* ls   = (const float*)d_in[2];   // (1,)
  float* out = (float*)d_out;
  float* ws = (float*)d_ws;
  float* clipn = ws + OFF_CLIPN;
  float* invv  = ws + OFF_INV;
  float* graw  = ws + OFF_GRAW;
  float* gnorm = ws + OFF_GNORM;
  float* Sglob = ws + OFF_SGLOB;
  float* Ssoft = ws + OFF_SSOFT;
  float* Shard = ws + OFF_SHARD;
  float* misc  = ws + OFF_MISC;

  k_misc<<<1, 64, 0, stream>>>(ls, misc);
  k_rownorm<<<256, 256, 0, stream>>>(clip, clipn);
  k_colnorm<<<256, 512, 0, stream>>>(yolo, invv);
  k_global_acc<<<dim3(16, 256), 512, 0, stream>>>(yolo, invv, graw);
  k_rownorm<<<256, 256, 0, stream>>>(graw, gnorm);
  k_simglobal<<<256, 256, 0, stream>>>(gnorm, clipn, misc, Sglob);
  k_main<<<256, 512, 0, stream>>>(yolo, clipn, invv, misc, Ssoft, Shard);
  k_focal<<<dim3(256, 6), 256, 0, stream>>>(Sglob, Ssoft, Shard, misc);
  k_finish<<<1, 1, 0, stream>>>(misc, out);
}

// Round 2
// 565.381 us; speedup vs baseline: 1.5284x; 1.5284x over previous
//
#include <hip/hip_runtime.h>
#include <math.h>

// Problem constants
constexpr int B = 256;
constexpr int C = 512;
constexpr int N = 512;
constexpr int K = 256;   // = B

// ws layout (floats)
constexpr size_t OFF_CLIPN  = 0;                          // B*C fp32
constexpr size_t OFF_CLIPNB = OFF_CLIPN + (size_t)B*C;    // B*C ushort = B*C/2 floats
constexpr size_t OFF_INV    = OFF_CLIPNB + (size_t)B*C/2; // B*N
constexpr size_t OFF_GRAW   = OFF_INV   + (size_t)B*N;    // B*C
constexpr size_t OFF_GNORM  = OFF_GRAW  + (size_t)B*C;    // B*C
constexpr size_t OFF_SGLOB  = OFF_GNORM + (size_t)B*C;    // B*K
constexpr size_t OFF_SSOFT  = OFF_SGLOB + (size_t)B*K;    // B*K
constexpr size_t OFF_SHARD  = OFF_SSOFT + (size_t)B*K;    // B*K
constexpr size_t OFF_PM     = OFF_SHARD + (size_t)B*K;    // 2*B*K partial m
constexpr size_t OFF_PS     = OFF_PM    + (size_t)2*B*K;  // 2*B*K partial s
constexpr size_t OFF_PH     = OFF_PS    + (size_t)2*B*K;  // 2*B*K partial h
constexpr size_t OFF_MISC   = OFF_PH    + (size_t)2*B*K;  // 7

typedef __attribute__((ext_vector_type(8))) short short8;
typedef __attribute__((ext_vector_type(4))) float f32x4;

__device__ __forceinline__ float wave_reduce_sum(float v) {
  #pragma unroll
  for (int off = 32; off > 0; off >>= 1) v += __shfl_xor(v, off, 64);
  return v;
}
__device__ __forceinline__ float wave_reduce_max(float v) {
  #pragma unroll
  for (int off = 32; off > 0; off >>= 1) v = fmaxf(v, __shfl_xor(v, off, 64));
  return v;
}
__device__ __forceinline__ unsigned int bf16_rne(float x) {
  unsigned int u = __builtin_bit_cast(unsigned int, x);
  return (u + 0x7FFFu + ((u >> 16) & 1u)) >> 16;
}
__device__ __forceinline__ unsigned int pk_bf16(float x, float y) {
  return bf16_rne(x) | (bf16_rne(y) << 16);
}

// ---------------- K0: scale + zero focal accumulators ----------------
__global__ void k_misc(const float* __restrict__ ls, float* __restrict__ misc) {
  int t = threadIdx.x;
  if (t == 0) misc[0] = fminf(fmaxf(expf(ls[0]), 0.01f), 100.0f);
  if (t >= 1 && t < 7) misc[t] = 0.0f;
}

// ---------------- K1: l2-normalize 256 rows of 512 (+ optional bf16 copy) ----------------
__global__ __launch_bounds__(256) void k_rownorm(const float* __restrict__ src,
                                                 float* __restrict__ dst,
                                                 unsigned short* __restrict__ dst_bf) {
  int b = blockIdx.x, t = threadIdx.x;
  float x0 = src[(size_t)b * C + t];
  float x1 = src[(size_t)b * C + t + 256];
  __shared__ float red[4];
  float w = wave_reduce_sum(x0 * x0 + x1 * x1);
  if ((t & 63) == 0) red[t >> 6] = w;
  __syncthreads();
  float tot = red[0] + red[1] + red[2] + red[3];
  float r = 1.0f / fmaxf(sqrtf(tot), 1e-12f);
  float y0 = x0 * r, y1 = x1 * r;
  dst[(size_t)b * C + t] = y0;
  dst[(size_t)b * C + t + 256] = y1;
  if (dst_bf) {
    dst_bf[(size_t)b * C + t] = (unsigned short)bf16_rne(y0);
    dst_bf[(size_t)b * C + t + 256] = (unsigned short)bf16_rne(y1);
  }
}

// ---------------- K2: yolo column inverse norms: inv[b][n] ----------------
__global__ __launch_bounds__(512) void k_colnorm(const float* __restrict__ yolo,
                                                 float* __restrict__ inv) {
  int b = blockIdx.x, t = threadIdx.x;
  int cq = t >> 7;        // 0..3 (c quarter)
  int nq = t & 127;       // 0..127 (n quad)
  const float* p = yolo + (size_t)b * C * N + (size_t)cq * 128 * N + nq * 4;
  float4 ss = {0.f, 0.f, 0.f, 0.f};
  #pragma unroll 8
  for (int c = 0; c < 128; c++) {
    float4 v = *(const float4*)(p + (size_t)c * N);
    ss.x += v.x * v.x; ss.y += v.y * v.y; ss.z += v.z * v.z; ss.w += v.w * v.w;
  }
  __shared__ float4 sm[4][128];
  sm[cq][nq] = ss;
  __syncthreads();
  if (t < 128) {
    float4 a = sm[0][t], b4 = sm[1][t], c4 = sm[2][t], d4 = sm[3][t];
    float4 r;
    r.x = 1.0f / fmaxf(sqrtf(a.x + b4.x + c4.x + d4.x), 1e-12f);
    r.y = 1.0f / fmaxf(sqrtf(a.y + b4.y + c4.y + d4.y), 1e-12f);
    r.z = 1.0f / fmaxf(sqrtf(a.z + b4.z + c4.z + d4.z), 1e-12f);
    r.w = 1.0f / fmaxf(sqrtf(a.w + b4.w + c4.w + d4.w), 1e-12f);
    *(float4*)(inv + (size_t)b * N + t * 4) = r;
  }
}

// ---------------- K3: graw[b][c] = (1/N) * sum_n yolo[b][c][n]*inv[b][n] ----------------
__global__ __launch_bounds__(512) void k_global_acc(const float* __restrict__ yolo,
                                                    const float* __restrict__ inv,
                                                    float* __restrict__ graw) {
  int b = blockIdx.y;
  int c0 = blockIdx.x * 32;
  int t = threadIdx.x;
  int ci = t >> 7;    // 0..3
  int nq = t & 127;   // 0..127
  float4 i4 = *(const float4*)(inv + (size_t)b * N + nq * 4);
  __shared__ float sm[8];
  const float* base = yolo + (size_t)b * C * N;
  for (int r = 0; r < 8; r++) {
    int c = c0 + r * 4 + ci;
    float4 v = *(const float4*)(base + (size_t)c * N + nq * 4);
    float p = v.x * i4.x + v.y * i4.y + v.z * i4.z + v.w * i4.w;
    float w = wave_reduce_sum(p);
    if ((t & 63) == 0) sm[t >> 6] = w;
    __syncthreads();
    if (t < 4) graw[(size_t)b * C + c0 + r * 4 + t] =
        (sm[2 * t] + sm[2 * t + 1]) * (1.0f / (float)N);
    __syncthreads();
  }
}

// ---------------- K4: Sglob[i][k] = scale * dot(gnorm[i], clipn[k]) ----------------
__global__ __launch_bounds__(256) void k_simglobal(const float* __restrict__ gnorm,
                                                   const float* __restrict__ clipn,
                                                   const float* __restrict__ misc,
                                                   float* __restrict__ Sglob) {
  int i = blockIdx.x, k = threadIdx.x;
  __shared__ float g[C];
  g[k] = gnorm[(size_t)i * C + k];
  g[k + 256] = gnorm[(size_t)i * C + k + 256];
  __syncthreads();
  float scale = misc[0];
  const float* cr = clipn + (size_t)k * C;
  float acc = 0.f;
  #pragma unroll 4
  for (int c = 0; c < C; c += 4) {
    float4 cv = *(const float4*)(cr + c);
    acc += cv.x * g[c] + cv.y * g[c + 1] + cv.z * g[c + 2] + cv.w * g[c + 3];
  }
  Sglob[(size_t)i * K + k] = acc * scale;
}

// ---------------- K5: main GEMM via bf16 MFMA + online logsumexp/max over n ----------
// grid 512: block bh -> b = bh>>1, half = bh&1 (n in [half*256, half*256+256))
// 256 threads = 4 waves; wave w owns k in [64w, 64w+64) as 4 ktiles of 16.
// Per n-iter of 128: 8 ntiles. acc[kt][nt] = 16x16 MFMA tile frag (4 floats).
// LDS rows: 32 data dwords + 1 pad (stride 33 dwords = 66 bf16) -> transpose
// column-writes are conflict-free (bank step 33 mod 32 = 1), frag reads are
// 4 adjacent dwords (ds_read2_b32, no 16B-alignment need).
__global__ __launch_bounds__(256, 2) void k_main_mfma(
    const float* __restrict__ yolo,
    const unsigned short* __restrict__ clipnb,
    const float* __restrict__ inv,
    const float* __restrict__ misc,
    float* __restrict__ PM, float* __restrict__ PS, float* __restrict__ PH) {
  int bh = blockIdx.x;
  int b = bh >> 1, half = bh & 1;
  int t = threadIdx.x;
  int w = t >> 6, lane = t & 63;
  int quad = lane >> 4, col = lane & 15;

  __shared__ unsigned int xl[128 * 33];  // X chunk transposed: [n_local][c-pair dwords]
  __shared__ unsigned int wl[256 * 33];  // W chunk: [k][c-pair dwords]
  __shared__ float invt[128];

  const float scale = misc[0];
  const float* ybase = yolo + (size_t)b * C * N;

  float msk[16], ssk[16], hsk[16];
  #pragma unroll
  for (int i = 0; i < 16; i++) { msk[i] = -1e30f; ssk[i] = 0.f; hsk[i] = -1e30f; }

  for (int iter = 0; iter < 2; iter++) {
    int n0 = half * 256 + iter * 128;
    __syncthreads();                       // prev iter epilogue done before invt rewrite
    if (t < 128) invt[t] = inv[(size_t)b * N + n0 + t] * scale;

    f32x4 acc[4][8];
    #pragma unroll
    for (int kt = 0; kt < 4; kt++)
      #pragma unroll
      for (int nt = 0; nt < 8; nt++) {
        f32x4 z = {0.f, 0.f, 0.f, 0.f};
        acc[kt][nt] = z;
      }

    for (int cc = 0; cc < 8; cc++) {
      int c0 = cc * 64;
      __syncthreads();                     // prev chunk compute done
      // ---- stage X: 64 c x 128 n, fp32 -> bf16, transpose to [n][c] ----
      {
        int nf = t & 31;                   // n-float4 index (4 n's)
        int cp0 = t >> 5;                  // 0..7
        #pragma unroll
        for (int p = 0; p < 4; p++) {
          int cp = cp0 + 8 * p;            // c-pair 0..31
          int c = c0 + 2 * cp;
          const float* pa = ybase + (size_t)c * N + n0 + 4 * nf;
          float4 a = *(const float4*)pa;
          float4 bb = *(const float4*)(pa + N);
          int row = 4 * nf;
          xl[33 * (row + 0) + cp] = pk_bf16(a.x, bb.x);
          xl[33 * (row + 1) + cp] = pk_bf16(a.y, bb.y);
          xl[33 * (row + 2) + cp] = pk_bf16(a.z, bb.z);
          xl[33 * (row + 3) + cp] = pk_bf16(a.w, bb.w);
        }
      }
      // ---- stage W: 256 k x 64 c bf16 ----
      {
        #pragma unroll
        for (int i = 0; i < 8; i++) {
          int slot = t + 256 * i;
          int k = slot >> 3, g = slot & 7;
          uint4 v = *(const uint4*)(clipnb + (size_t)k * C + c0 + 8 * g);
          int o = 33 * k + 4 * g;
          wl[o + 0] = v.x; wl[o + 1] = v.y; wl[o + 2] = v.z; wl[o + 3] = v.w;
        }
      }
      __syncthreads();
      // ---- MFMA phase ----
      #pragma unroll
      for (int s = 0; s < 2; s++) {
        int cofs = 16 * s + 4 * quad;
        short8 afr[4];
        #pragma unroll
        for (int kt = 0; kt < 4; kt++) {
          int o = 33 * (64 * w + 16 * kt + col) + cofs;
          union { unsigned int u[4]; short8 v; } fa;
          fa.u[0] = wl[o]; fa.u[1] = wl[o + 1]; fa.u[2] = wl[o + 2]; fa.u[3] = wl[o + 3];
          afr[kt] = fa.v;
        }
        #pragma unroll
        for (int nt = 0; nt < 8; nt++) {
          int o = 33 * (16 * nt + col) + cofs;
          union { unsigned int u[4]; short8 v; } fb;
          fb.u[0] = xl[o]; fb.u[1] = xl[o + 1]; fb.u[2] = xl[o + 2]; fb.u[3] = xl[o + 3];
          #pragma unroll
          for (int kt = 0; kt < 4; kt++)
            acc[kt][nt] = __builtin_amdgcn_mfma_f32_16x16x32_bf16(afr[kt], fb.v,
                                                                  acc[kt][nt], 0, 0, 0);
        }
      }
    }
    // ---- iter epilogue: fold inv*scale, online (m,s,h) over this iter's 128 n ----
    float invn[8];
    #pragma unroll
    for (int nt = 0; nt < 8; nt++) invn[nt] = invt[16 * nt + col];
    #pragma unroll
    for (int kt = 0; kt < 4; kt++)
      #pragma unroll
      for (int r = 0; r < 4; r++) {
        int idx = kt * 4 + r;
        float mm = msk[idx], ss = ssk[idx], hh = hsk[idx];
        #pragma unroll
        for (int nt = 0; nt < 8; nt++) {
          float v = acc[kt][nt][r] * invn[nt];
          hh = fmaxf(hh, v);
          float M = fmaxf(mm, v);
          ss = ss * __expf(mm - M) + __expf(v - M);
          mm = M;
        }
        msk[idx] = mm; ssk[idx] = ss; hsk[idx] = hh;
      }
  }
  // ---- reduce (m,s,h) across the 16 lanes of each quad (cols) ----
  #pragma unroll
  for (int idx = 0; idx < 16; idx++) {
    float mm = msk[idx], ss = ssk[idx], hh = hsk[idx];
    #pragma unroll
    for (int o = 1; o < 16; o <<= 1) {
      float mo = __shfl_xor(mm, o, 64);
      float so = __shfl_xor(ss, o, 64);
      float ho = __shfl_xor(hh, o, 64);
      float M = fmaxf(mm, mo);
      ss = ss * __expf(mm - M) + so * __expf(mo - M);
      mm = M;
      hh = fmaxf(hh, ho);
    }
    msk[idx] = mm; ssk[idx] = ss; hsk[idx] = hh;
  }
  if (col == 0) {
    size_t pbase = (size_t)bh * 256;
    #pragma unroll
    for (int kt = 0; kt < 4; kt++)
      #pragma unroll
      for (int r = 0; r < 4; r++) {
        int k = 64 * w + 16 * kt + 4 * quad + r;
        int idx = kt * 4 + r;
        PM[pbase + k] = msk[idx];
        PS[pbase + k] = ssk[idx];
        PH[pbase + k] = hsk[idx];
      }
  }
}

// ---------------- K5b: merge the two n-halves -> Ssoft, Shard ----------------
__global__ __launch_bounds__(256) void k_merge(const float* __restrict__ PM,
                                               const float* __restrict__ PS,
                                               const float* __restrict__ PH,
                                               float* __restrict__ Ssoft,
                                               float* __restrict__ Shard) {
  int b = blockIdx.x, k = threadIdx.x;
  size_t p0 = (size_t)(2 * b) * 256 + k;
  size_t p1 = (size_t)(2 * b + 1) * 256 + k;
  float m0 = PM[p0], m1 = PM[p1];
  float M = fmaxf(m0, m1);
  float S = PS[p0] * __expf(m0 - M) + PS[p1] * __expf(m1 - M);
  Ssoft[(size_t)b * K + k] = M + __logf(S);
  Shard[(size_t)b * K + k] = fmaxf(PH[p0], PH[p1]);
}

// ---------------- K6: focal CE per row/col of each 256x256 matrix ----------------
__global__ __launch_bounds__(256) void k_focal(const float* __restrict__ Sglob,
                                               const float* __restrict__ Ssoft,
                                               const float* __restrict__ Shard,
                                               float* __restrict__ misc) {
  int job = blockIdx.y;   // 0..5: {glob,globT,soft,softT,hard,hardT}
  int i = blockIdx.x;
  int t = threadIdx.x;
  const float* M = job < 2 ? Sglob : (job < 4 ? Ssoft : Shard);
  float v = (job & 1) ? M[(size_t)t * K + i] : M[(size_t)i * K + t];
  __shared__ float red[4];
  float mx = wave_reduce_max(v);
  if ((t & 63) == 0) red[t >> 6] = mx;
  __syncthreads();
  mx = fmaxf(fmaxf(red[0], red[1]), fmaxf(red[2], red[3]));
  __syncthreads();
  float sv = wave_reduce_sum(v);
  if ((t & 63) == 0) red[t >> 6] = sv;
  __syncthreads();
  float sumv = red[0] + red[1] + red[2] + red[3];
  __syncthreads();
  float se = wave_reduce_sum(expf(v - mx));
  if ((t & 63) == 0) red[t >> 6] = se;
  __syncthreads();
  if (t == 0) {
    float sumexp = red[0] + red[1] + red[2] + red[3];
    float logZ = mx + logf(sumexp);
    float diag = M[(size_t)i * K + i];
    float nll = logZ - diag;                      // -log_p[label]
    float smooth = logZ - sumv * (1.0f / 256.0f); // -mean(log_p)
    float ce = 0.75f * nll + 0.25f * smooth;
    float pt = expf(-ce);
    float fo = (1.0f - pt) * (1.0f - pt) * ce;
    atomicAdd(&misc[1 + job], fo);
  }
}

// ---------------- K7: combine ----------------
__global__ void k_finish(const float* __restrict__ misc, float* __restrict__ out) {
  float lg = misc[1] + misc[2];
  float ls = misc[3] + misc[4];
  float lh = misc[5] + misc[6];
  out[0] = (0.2f * lg + 0.3f * ls + 0.5f * lh) * 0.5f * (1.0f / 256.0f);
}

extern "C" void kernel_launch(void* const* d_in, const int* in_sizes, int n_in,
                              void* d_out, int out_size, void* d_ws, size_t ws_size,
                              hipStream_t stream) {
  const float* yolo = (const float*)d_in[0];   // (B, C, N)
  const float* clip = (const float*)d_in[1];   // (B, C)
  const float* ls   = (const float*)d_in[2];   // (1,)
  float* out = (float*)d_out;
  float* ws = (float*)d_ws;
  float* clipn = ws + OFF_CLIPN;
  unsigned short* clipnb = (unsigned short*)(ws + OFF_CLIPNB);
  float* invv  = ws + OFF_INV;
  float* graw  = ws + OFF_GRAW;
  float* gnorm = ws + OFF_GNORM;
  float* Sglob = ws + OFF_SGLOB;
  float* Ssoft = ws + OFF_SSOFT;
  float* Shard = ws + OFF_SHARD;
  float* PM    = ws + OFF_PM;
  float* PS    = ws + OFF_PS;
  float* PH    = ws + OFF_PH;
  float* misc  = ws + OFF_MISC;

  k_misc<<<1, 64, 0, stream>>>(ls, misc);
  k_rownorm<<<256, 256, 0, stream>>>(clip, clipn, clipnb);
  k_colnorm<<<256, 512, 0, stream>>>(yolo, invv);
  k_global_acc<<<dim3(16, 256), 512, 0, stream>>>(yolo, invv, graw);
  k_rownorm<<<256, 256, 0, stream>>>(graw, gnorm, (unsigned short*)nullptr);
  k_simglobal<<<256, 256, 0, stream>>>(gnorm, clipn, misc, Sglob);
  k_main_mfma<<<512, 256, 0, stream>>>(yolo, clipnb, invv, misc, PM, PS, PH);
  k_merge<<<256, 256, 0, stream>>>(PM, PS, PH, Ssoft, Shard);
  k_focal<<<dim3(256, 6), 256, 0, stream>>>(Sglob, Ssoft, Shard, misc);
  k_finish<<<1, 1, 0, stream>>>(misc, out);
}

// Round 3
// 477.360 us; speedup vs baseline: 1.8102x; 1.1844x over previous
//
#include <hip/hip_runtime.h>
#include <math.h>

// Problem constants
constexpr int B = 256;
constexpr int C = 512;
constexpr int N = 512;
constexpr int K = 256;   // = B

// ws layout (floats)
constexpr size_t OFF_CLIPNB = 0;                            // B*C bf16 = B*C/2 floats
constexpr size_t OFF_INV    = OFF_CLIPNB + (size_t)B*C/2;   // B*N
constexpr size_t OFF_SGLOB  = OFF_INV   + (size_t)B*N;      // B*K
constexpr size_t OFF_SSOFT  = OFF_SGLOB + (size_t)B*K;      // B*K
constexpr size_t OFF_SHARD  = OFF_SSOFT + (size_t)B*K;      // B*K
constexpr size_t OFF_PM     = OFF_SHARD + (size_t)B*K;      // 2*B*K
constexpr size_t OFF_PS     = OFF_PM    + (size_t)2*B*K;    // 2*B*K
constexpr size_t OFF_PH     = OFF_PS    + (size_t)2*B*K;    // 2*B*K
constexpr size_t OFF_PG     = OFF_PH    + (size_t)2*B*K;    // 2*B*K
constexpr size_t OFF_GN     = OFF_PG    + (size_t)2*B*K;    // B
constexpr size_t OFF_MISC   = OFF_GN    + (size_t)B;        // 7

typedef __attribute__((ext_vector_type(8))) short short8;
typedef __attribute__((ext_vector_type(4))) float f32x4;

__device__ __forceinline__ float wave_reduce_sum(float v) {
  #pragma unroll
  for (int off = 32; off > 0; off >>= 1) v += __shfl_xor(v, off, 64);
  return v;
}
__device__ __forceinline__ float wave_reduce_max(float v) {
  #pragma unroll
  for (int off = 32; off > 0; off >>= 1) v = fmaxf(v, __shfl_xor(v, off, 64));
  return v;
}
__device__ __forceinline__ unsigned int bf16_rne(float x) {
  unsigned int u = __builtin_bit_cast(unsigned int, x);
  return (u + 0x7FFFu + ((u >> 16) & 1u)) >> 16;
}
__device__ __forceinline__ unsigned int pk_bf16(float x, float y) {
  return bf16_rne(x) | (bf16_rne(y) << 16);
}

// ---------------- K0: scale + zero focal accumulators ----------------
__global__ void k_misc(const float* __restrict__ ls, float* __restrict__ misc) {
  int t = threadIdx.x;
  if (t == 0) misc[0] = fminf(fmaxf(expf(ls[0]), 0.01f), 100.0f);
  if (t >= 1 && t < 7) misc[t] = 0.0f;
}

// ---------------- K1: l2-normalize clip rows -> bf16 ----------------
__global__ __launch_bounds__(256) void k_rownorm(const float* __restrict__ src,
                                                 unsigned short* __restrict__ dst_bf) {
  int b = blockIdx.x, t = threadIdx.x;
  float x0 = src[(size_t)b * C + t];
  float x1 = src[(size_t)b * C + t + 256];
  __shared__ float red[4];
  float w = wave_reduce_sum(x0 * x0 + x1 * x1);
  if ((t & 63) == 0) red[t >> 6] = w;
  __syncthreads();
  float tot = red[0] + red[1] + red[2] + red[3];
  float r = 1.0f / fmaxf(sqrtf(tot), 1e-12f);
  dst_bf[(size_t)b * C + t] = (unsigned short)bf16_rne(x0 * r);
  dst_bf[(size_t)b * C + t + 256] = (unsigned short)bf16_rne(x1 * r);
}

// ---------------- K2: fused main GEMM (bf16 MFMA) ----------------
// grid 512: block bh -> b = bh>>1, half = bh&1 (n in [half*256, half*256+256))
// 256 threads = 4 waves; wave w owns k in [64w, 64w+64) as 4 ktiles of 16.
// Per 128-n iter: 8 ntiles, acc[kt][nt] = 16x16 frag (4 f32).
// Fused: ssq[n] accumulated during staging -> inv computed in-block (kills
// k_colnorm); epilogue also accumulates gsum[k] = sum_n rawsim*inv, which is
// clip_k . yolo_global_b * N (kills k_global_acc + k_simglobal GEMM).
// A-frags come straight from global clipnb (256 KB, L2-resident) - no LDS tile.
// xl layout: row n = 32 dwords (64 bf16 c's), rotated by rot(n)=8*((n>>2)&3)+4*(n>>4):
//  - frag reads: 16B-aligned ds_read_b128, exactly 8 bank-touches/bank (optimal)
//  - transpose writes: 4-way conflict only (1.58x, acceptable; write b32 is scatter by nature)
__global__ __launch_bounds__(256, 2) void k_main_mfma(
    const float* __restrict__ yolo,
    const unsigned short* __restrict__ clipnb,
    const float* __restrict__ misc,
    float* __restrict__ invg,
    float* __restrict__ PM, float* __restrict__ PS, float* __restrict__ PH,
    float* __restrict__ PG) {
  int bh = blockIdx.x;
  int b = bh >> 1, half = bh & 1;
  int t = threadIdx.x;
  int w = t >> 6, lane = t & 63;
  int quad = lane >> 4, col = lane & 15;

  __shared__ unsigned int xl[128 * 32];   // 16 KB, rotated rows
  __shared__ float ssqb[8 * 128];         // 4 KB
  __shared__ float invt[128];

  const float scale = misc[0];
  const float* ybase = yolo + (size_t)b * C * N;

  // staging decomposition
  int nf = t & 31;                 // 4-n group (n = 4nf+j)
  int cp0 = t >> 5;                // 0..7 (c-pair subset)
  unsigned int rotv = (8u * (nf & 3) + 4u * (unsigned)(nf >> 2)) & 31u;

  float msk[16], ssk[16], hsk[16];
  #pragma unroll
  for (int i = 0; i < 16; i++) { msk[i] = -1e30f; ssk[i] = 0.f; hsk[i] = -1e30f; }

  for (int iter = 0; iter < 2; iter++) {
    int n0 = half * 256 + iter * 128;
    float4 ssq4 = {0.f, 0.f, 0.f, 0.f};

    f32x4 acc[4][8];
    #pragma unroll
    for (int kt = 0; kt < 4; kt++)
      #pragma unroll
      for (int nt = 0; nt < 8; nt++) {
        f32x4 z = {0.f, 0.f, 0.f, 0.f};
        acc[kt][nt] = z;
      }

    for (int cc = 0; cc < 8; cc++) {
      int c0 = cc * 64;
      __syncthreads();               // prev chunk frag reads done before xl rewrite

      // ---- A-frags from global (L2-hot), issued early to hide latency ----
      short8 afr[4][2];
      #pragma unroll
      for (int kt = 0; kt < 4; kt++)
        #pragma unroll
        for (int s = 0; s < 2; s++) {
          const unsigned short* ap =
              clipnb + (size_t)(64 * w + 16 * kt + col) * C + c0 + 32 * s + 8 * quad;
          union { uint4 u; short8 v; } fa;
          fa.u = *(const uint4*)ap;
          afr[kt][s] = fa.v;
        }

      // ---- stage X: 64 c x 128 n, fp32 -> bf16, transpose, + ssq ----
      #pragma unroll
      for (int p = 0; p < 4; p++) {
        int cp = cp0 + 8 * p;        // c-pair 0..31
        int c = c0 + 2 * cp;
        const float* pa = ybase + (size_t)c * N + n0 + 4 * nf;
        float4 a = *(const float4*)pa;
        float4 bb = *(const float4*)(pa + N);
        ssq4.x += a.x * a.x + bb.x * bb.x;
        ssq4.y += a.y * a.y + bb.y * bb.y;
        ssq4.z += a.z * a.z + bb.z * bb.z;
        ssq4.w += a.w * a.w + bb.w * bb.w;
        unsigned int pos = ((unsigned)cp + rotv) & 31u;
        int base0 = (4 * nf) * 32;
        xl[base0 + pos]       = pk_bf16(a.x, bb.x);
        xl[base0 + 32 + pos]  = pk_bf16(a.y, bb.y);
        xl[base0 + 64 + pos]  = pk_bf16(a.z, bb.z);
        xl[base0 + 96 + pos]  = pk_bf16(a.w, bb.w);
      }
      __syncthreads();

      // ---- MFMA phase: b128 frag reads, optimal bank tiling ----
      #pragma unroll
      for (int s = 0; s < 2; s++) {
        #pragma unroll
        for (int nt = 0; nt < 8; nt++) {
          int n = 16 * nt + col;
          unsigned int pos =
              (unsigned)(16 * s + 4 * quad + 8 * (col >> 2) + 4 * nt) & 31u;
          union { uint4 u; short8 v; } fb;
          fb.u = *(const uint4*)&xl[n * 32 + pos];
          #pragma unroll
          for (int kt = 0; kt < 4; kt++)
            acc[kt][nt] = __builtin_amdgcn_mfma_f32_16x16x32_bf16(
                afr[kt][s], fb.v, acc[kt][nt], 0, 0, 0);
        }
      }
    }

    // ---- ssq reduce -> inv for this 128-n window ----
    {
      int base = cp0 * 128 + 4 * nf;
      ssqb[base + 0] = ssq4.x;
      ssqb[base + 1] = ssq4.y;
      ssqb[base + 2] = ssq4.z;
      ssqb[base + 3] = ssq4.w;
    }
    __syncthreads();
    if (t < 128) {
      float s = 0.f;
      #pragma unroll
      for (int g = 0; g < 8; g++) s += ssqb[g * 128 + t];
      float iv = 1.0f / fmaxf(sqrtf(s), 1e-12f);
      invt[t] = iv;
      invg[(size_t)b * N + n0 + t] = iv;
    }
    __syncthreads();

    // ---- epilogue: fold inv, online (m,s,h), gsum for global branch ----
    float invn[8];
    #pragma unroll
    for (int nt = 0; nt < 8; nt++) invn[nt] = invt[16 * nt + col];
    #pragma unroll
    for (int kt = 0; kt < 4; kt++)
      #pragma unroll
      for (int r = 0; r < 4; r++) {
        int idx = kt * 4 + r;
        float mm = msk[idx], ss = ssk[idx], hh = hsk[idx], gg = 0.f;
        #pragma unroll
        for (int nt = 0; nt < 8; nt++) {
          float vu = acc[kt][nt][r] * invn[nt];
          gg += vu;
          float v = vu * scale;
          hh = fmaxf(hh, v);
          float M = fmaxf(mm, v);
          ss = ss * __expf(mm - M) + __expf(v - M);
          mm = M;
        }
        msk[idx] = mm; ssk[idx] = ss; hsk[idx] = hh;
        // reduce gsum over the 16 cols (n) of this quad
        #pragma unroll
        for (int o = 1; o < 16; o <<= 1) gg += __shfl_xor(gg, o, 64);
        if (col == 0) {
          size_t a = (size_t)bh * 256 + (64 * w + 16 * kt + 4 * quad + r);
          if (iter == 0) PG[a] = gg; else PG[a] += gg;
        }
      }
  }

  // ---- reduce (m,s,h) across the 16 cols of each quad ----
  #pragma unroll
  for (int idx = 0; idx < 16; idx++) {
    float mm = msk[idx], ss = ssk[idx], hh = hsk[idx];
    #pragma unroll
    for (int o = 1; o < 16; o <<= 1) {
      float mo = __shfl_xor(mm, o, 64);
      float so = __shfl_xor(ss, o, 64);
      float ho = __shfl_xor(hh, o, 64);
      float M = fmaxf(mm, mo);
      ss = ss * __expf(mm - M) + so * __expf(mo - M);
      mm = M;
      hh = fmaxf(hh, ho);
    }
    msk[idx] = mm; ssk[idx] = ss; hsk[idx] = hh;
  }
  if (col == 0) {
    size_t pbase = (size_t)bh * 256;
    #pragma unroll
    for (int kt = 0; kt < 4; kt++)
      #pragma unroll
      for (int r = 0; r < 4; r++) {
        int k = 64 * w + 16 * kt + 4 * quad + r;
        int idx = kt * 4 + r;
        PM[pbase + k] = msk[idx];
        PS[pbase + k] = ssk[idx];
        PH[pbase + k] = hsk[idx];
      }
  }
}

// ---------------- K3: gn[b] = max(||graw_b||, eps) ----------------
// graw[b][c] = (1/N) sum_n yolo[b][c][n]*inv[b][n]; only the norm is needed
// (the direction's dot with clip comes from PG).
__global__ __launch_bounds__(512) void k_gnorm(const float* __restrict__ yolo,
                                               const float* __restrict__ invg,
                                               float* __restrict__ gn) {
  int b = blockIdx.x;
  int t = threadIdx.x;
  int w = t >> 6, lane = t & 63;
  const float* xb = yolo + (size_t)b * C * N;
  const float* ivb = invg + (size_t)b * N;
  float4 iv[2];
  #pragma unroll
  for (int p = 0; p < 2; p++) iv[p] = *(const float4*)(ivb + p * 256 + 4 * lane);
  float sq = 0.f;
  for (int ci = 0; ci < 64; ci++) {
    int c = w * 64 + ci;
    const float* row = xb + (size_t)c * N + 4 * lane;
    float cs = 0.f;
    #pragma unroll
    for (int p = 0; p < 2; p++) {
      float4 v = *(const float4*)(row + p * 256);
      cs += v.x * iv[p].x + v.y * iv[p].y + v.z * iv[p].z + v.w * iv[p].w;
    }
    cs = wave_reduce_sum(cs);
    sq += cs * cs;      // identical on all lanes post-butterfly
  }
  __shared__ float red[8];
  if (lane == 0) red[w] = sq;
  __syncthreads();
  if (t == 0) {
    float s = 0.f;
    #pragma unroll
    for (int g = 0; g < 8; g++) s += red[g];
    gn[b] = fmaxf(sqrtf(s) * (1.0f / (float)N), 1e-12f);
  }
}

// ---------------- K4: Sglob from PG + gn ----------------
__global__ __launch_bounds__(256) void k_sglob(const float* __restrict__ PG,
                                               const float* __restrict__ gn,
                                               const float* __restrict__ misc,
                                               float* __restrict__ Sglob) {
  int i = blockIdx.x, k = threadIdx.x;
  float v = PG[(size_t)(2 * i) * 256 + k] + PG[(size_t)(2 * i + 1) * 256 + k];
  // graw.clip = v/N ; Sglob = scale * (graw.clip) / ||graw||
  Sglob[(size_t)i * K + k] = misc[0] * v * (1.0f / (float)N) / gn[i];
}

// ---------------- K5: merge the two n-halves -> Ssoft, Shard ----------------
__global__ __launch_bounds__(256) void k_merge(const float* __restrict__ PM,
                                               const float* __restrict__ PS,
                                               const float* __restrict__ PH,
                                               float* __restrict__ Ssoft,
                                               float* __restrict__ Shard) {
  int b = blockIdx.x, k = threadIdx.x;
  size_t p0 = (size_t)(2 * b) * 256 + k;
  size_t p1 = (size_t)(2 * b + 1) * 256 + k;
  float m0 = PM[p0], m1 = PM[p1];
  float M = fmaxf(m0, m1);
  float S = PS[p0] * __expf(m0 - M) + PS[p1] * __expf(m1 - M);
  Ssoft[(size_t)b * K + k] = M + __logf(S);
  Shard[(size_t)b * K + k] = fmaxf(PH[p0], PH[p1]);
}

// ---------------- K6: focal CE per row/col of each 256x256 matrix ----------------
__global__ __launch_bounds__(256) void k_focal(const float* __restrict__ Sglob,
                                               const float* __restrict__ Ssoft,
                                               const float* __restrict__ Shard,
                                               float* __restrict__ misc) {
  int job = blockIdx.y;   // 0..5: {glob,globT,soft,softT,hard,hardT}
  int i = blockIdx.x;
  int t = threadIdx.x;
  const float* M = job < 2 ? Sglob : (job < 4 ? Ssoft : Shard);
  float v = (job & 1) ? M[(size_t)t * K + i] : M[(size_t)i * K + t];
  __shared__ float red[4];
  float mx = wave_reduce_max(v);
  if ((t & 63) == 0) red[t >> 6] = mx;
  __syncthreads();
  mx = fmaxf(fmaxf(red[0], red[1]), fmaxf(red[2], red[3]));
  __syncthreads();
  float sv = wave_reduce_sum(v);
  if ((t & 63) == 0) red[t >> 6] = sv;
  __syncthreads();
  float sumv = red[0] + red[1] + red[2] + red[3];
  __syncthreads();
  float se = wave_reduce_sum(expf(v - mx));
  if ((t & 63) == 0) red[t >> 6] = se;
  __syncthreads();
  if (t == 0) {
    float sumexp = red[0] + red[1] + red[2] + red[3];
    float logZ = mx + logf(sumexp);
    float diag = M[(size_t)i * K + i];
    float nll = logZ - diag;                      // -log_p[label]
    float smooth = logZ - sumv * (1.0f / 256.0f); // -mean(log_p)
    float ce = 0.75f * nll + 0.25f * smooth;
    float pt = expf(-ce);
    float fo = (1.0f - pt) * (1.0f - pt) * ce;
    atomicAdd(&misc[1 + job], fo);
  }
}

// ---------------- K7: combine ----------------
__global__ void k_finish(const float* __restrict__ misc, float* __restrict__ out) {
  float lg = misc[1] + misc[2];
  float ls = misc[3] + misc[4];
  float lh = misc[5] + misc[6];
  out[0] = (0.2f * lg + 0.3f * ls + 0.5f * lh) * 0.5f * (1.0f / 256.0f);
}

extern "C" void kernel_launch(void* const* d_in, const int* in_sizes, int n_in,
                              void* d_out, int out_size, void* d_ws, size_t ws_size,
                              hipStream_t stream) {
  const float* yolo = (const float*)d_in[0];   // (B, C, N)
  const float* clip = (const float*)d_in[1];   // (B, C)
  const float* ls   = (const float*)d_in[2];   // (1,)
  float* out = (float*)d_out;
  float* ws = (float*)d_ws;
  unsigned short* clipnb = (unsigned short*)(ws + OFF_CLIPNB);
  float* invg  = ws + OFF_INV;
  float* Sglob = ws + OFF_SGLOB;
  float* Ssoft = ws + OFF_SSOFT;
  float* Shard = ws + OFF_SHARD;
  float* PM    = ws + OFF_PM;
  float* PS    = ws + OFF_PS;
  float* PH    = ws + OFF_PH;
  float* PG    = ws + OFF_PG;
  float* gn    = ws + OFF_GN;
  float* misc  = ws + OFF_MISC;

  k_misc<<<1, 64, 0, stream>>>(ls, misc);
  k_rownorm<<<256, 256, 0, stream>>>(clip, clipnb);
  k_main_mfma<<<512, 256, 0, stream>>>(yolo, clipnb, misc, invg, PM, PS, PH, PG);
  k_gnorm<<<256, 512, 0, stream>>>(yolo, invg, gn);
  k_sglob<<<256, 256, 0, stream>>>(PG, gn, misc, Sglob);
  k_merge<<<256, 256, 0, stream>>>(PM, PS, PH, Ssoft, Shard);
  k_focal<<<dim3(256, 6), 256, 0, stream>>>(Sglob, Ssoft, Shard, misc);
  k_finish<<<1, 1, 0, stream>>>(misc, out);
}